// Round 1
// baseline (662.403 us; speedup 1.0000x reference)
//
#include <hip/hip_runtime.h>
#include <cstddef>

// SlotAttention restructured:
//   xn = LN(x) stored bf16 once; k,v never materialized.
//   logits = (LN(slots) @ Wqk + bqk) @ xn^T  with Wqk = SCALE*Wq^T@Wk  (q·bk const cancels in softmax)
//   gi     = (attn@xn) @ Wihv^T + bihv      with Wihv = W_ih@Wv, bihv = W_ih@bv + b_ih
//   (+1e-8 renorm dropped: perturbation ~2e-5 << threshold)

#define BB 64
#define NN 2048
#define DD 256
#define NCH 8     // n-chunks for attention partials
#define CHK 256   // n rows per chunk
#define NITER 3

typedef unsigned short u16;
typedef unsigned int u32;

__device__ __forceinline__ float bflo(u32 u){ return __uint_as_float(u<<16); }
__device__ __forceinline__ float bfhi(u32 u){ return __uint_as_float(u & 0xffff0000u); }
__device__ __forceinline__ u16 f2bf(float f){
  u32 u = __float_as_uint(f);
  u32 r = u + 0x7fffu + ((u>>16)&1u);
  return (u16)(r>>16);
}

// 256-thread block: mean + rstd over the 256 values (one per thread)
__device__ __forceinline__ float2 block_meanrstd(float v, float* sh){
  float s1=v, s2=v*v;
  #pragma unroll
  for(int off=1; off<64; off<<=1){ s1 += __shfl_xor(s1,off); s2 += __shfl_xor(s2,off); }
  int w = threadIdx.x>>6;
  if((threadIdx.x&63)==0){ sh[w]=s1; sh[4+w]=s2; }
  __syncthreads();
  float t1=sh[0]+sh[1]+sh[2]+sh[3];
  float t2=sh[4]+sh[5]+sh[6]+sh[7];
  float m = t1*(1.f/256.f);
  float var = t2*(1.f/256.f) - m*m;
  return make_float2(m, rsqrtf(var + 1e-5f));
}

// ---- slots init: mu + softplus(sigma)*noise ----
__global__ __launch_bounds__(256) void k_prep(const float* __restrict__ noise, const float* __restrict__ mu,
                                              const float* __restrict__ sig, float* __restrict__ S){
  int i = blockIdx.x*256 + threadIdx.x;      // < 64*8*256
  int d = i & 255;
  float sg = sig[d];
  float sp = fmaxf(sg, 0.f) + log1pf(expf(-fabsf(sg)));
  S[i] = mu[d] + sp * noise[i];
}

// ---- weight folds: Wqk = SCALE*Wq^T@Wk, bqk = SCALE*bq@Wk, Wihv = W_ih@Wv, bihv = W_ih@bv + b_ih ----
__global__ __launch_bounds__(256) void k_wpre(const float* __restrict__ Wq, const float* __restrict__ Wk,
                                              const float* __restrict__ bq, const float* __restrict__ Wih,
                                              const float* __restrict__ Wv, const float* __restrict__ bv,
                                              const float* __restrict__ bih,
                                              float* __restrict__ Wqk, float* __restrict__ bqk,
                                              float* __restrict__ Wihv, float* __restrict__ bihv){
  __shared__ float col[256];
  int blk = blockIdx.x, t = threadIdx.x;
  if(blk < 256){                 // Wqk row d1=blk
    col[t] = Wq[t*256 + blk];
    __syncthreads();
    float acc = 0.f;
    #pragma unroll 4
    for(int j=0;j<256;j++) acc += col[j]*Wk[j*256+t];
    Wqk[blk*256+t] = acc * 0.0625f;
  } else if(blk < 1024){         // Wihv row c
    int c = blk - 256;
    col[t] = Wih[c*256+t];
    __syncthreads();
    float acc = 0.f;
    #pragma unroll 4
    for(int j=0;j<256;j++) acc += col[j]*Wv[j*256+t];
    Wihv[c*256+t] = acc;
  } else if(blk == 1024){        // bqk
    float acc = 0.f;
    for(int j=0;j<256;j++) acc += bq[j]*Wk[j*256+t];
    bqk[t] = acc * 0.0625f;
  } else {                       // bihv (768)
    for(int c=t;c<768;c+=256){
      float acc = 0.f;
      for(int j=0;j<256;j++) acc += Wih[c*256+j]*bv[j];
      bihv[c] = acc + bih[c];
    }
  }
}

// ---- xn = LN(x)*g+b -> bf16 ; one wave per row ----
__global__ __launch_bounds__(256) void k_ln(const float* __restrict__ x, const float* __restrict__ g,
                                            const float* __restrict__ be, u16* __restrict__ xn){
  int wave = threadIdx.x>>6, lane = threadIdx.x&63;
  size_t row = (size_t)blockIdx.x*4 + wave;
  const float* xr = x + row*256;
  float4 v = *(const float4*)(xr + lane*4);
  float s1 = v.x+v.y+v.z+v.w;
  float s2 = v.x*v.x + v.y*v.y + v.z*v.z + v.w*v.w;
  #pragma unroll
  for(int off=1; off<64; off<<=1){ s1 += __shfl_xor(s1,off); s2 += __shfl_xor(s2,off); }
  float m = s1*(1.f/256.f);
  float var = s2*(1.f/256.f) - m*m;
  float rs = rsqrtf(var + 1e-5f);
  float4 gg = *(const float4*)(g + lane*4);
  float4 bb = *(const float4*)(be + lane*4);
  ushort4 o;
  o.x = f2bf((v.x-m)*rs*gg.x + bb.x);
  o.y = f2bf((v.y-m)*rs*gg.y + bb.y);
  o.z = f2bf((v.z-m)*rs*gg.z + bb.z);
  o.w = f2bf((v.w-m)*rs*gg.w + bb.w);
  *(ushort4*)(xn + row*256 + lane*4) = o;
}

// ---- q~ = LN_sl(slots) @ Wqk + bqk ; one block per (b,s) row ----
__global__ __launch_bounds__(256) void k_q(const float* __restrict__ Sc, const float* __restrict__ g,
                                           const float* __restrict__ be, const float* __restrict__ Wqk,
                                           const float* __restrict__ bqk, float* __restrict__ Q){
  __shared__ float ln[256];
  __shared__ float sh[8];
  int r = blockIdx.x, t = threadIdx.x;
  float v = Sc[r*256+t];
  float2 mr = block_meanrstd(v, sh);
  ln[t] = (v-mr.x)*mr.y*g[t] + be[t];
  __syncthreads();
  float acc = bqk[t];
  #pragma unroll 4
  for(int d=0; d<256; d++) acc += ln[d]*Wqk[d*256+t];
  Q[r*256+t] = acc;
}

// ---- attention partials: per (b, n-chunk): logits, online softmax, acc = p@xn ----
__global__ __launch_bounds__(256) void k_attn(const u16* __restrict__ xn, const float* __restrict__ Q,
                                              float* __restrict__ mP, float* __restrict__ lP,
                                              float* __restrict__ aP){
  __shared__ float qs[8][256];
  __shared__ float pl[8][256];
  __shared__ float mS[8], lS[8];
  const int b = blockIdx.x, c = blockIdx.y, t = threadIdx.x;
  for(int i=t;i<2048;i+=256) ((float*)qs)[i] = Q[b*2048 + i];
  __syncthreads();
  // logits for this thread's n-row
  const uint4* xr = (const uint4*)(xn + ((size_t)(b*NN) + (size_t)c*CHK + t)*DD);
  float lg[8]={0,0,0,0,0,0,0,0};
  #pragma unroll 2
  for(int d8=0; d8<32; ++d8){
    uint4 u = xr[d8];
    float x0=bflo(u.x), x1=bfhi(u.x), x2=bflo(u.y), x3=bfhi(u.y);
    float x4=bflo(u.z), x5=bfhi(u.z), x6=bflo(u.w), x7=bfhi(u.w);
    #pragma unroll
    for(int s=0;s<8;s++){
      const float* q = &qs[s][d8*8];
      lg[s] += q[0]*x0 + q[1]*x1 + q[2]*x2 + q[3]*x3
             + q[4]*x4 + q[5]*x5 + q[6]*x6 + q[7]*x7;
    }
  }
  #pragma unroll
  for(int s=0;s<8;s++) pl[s][t] = lg[s];
  __syncthreads();
  {  // per-s chunk max (32 lanes per s)
    int s = t>>5, l32 = t&31;
    float mx = -1e30f;
    #pragma unroll
    for(int k=0;k<8;k++) mx = fmaxf(mx, pl[s][l32 + 32*k]);
    #pragma unroll
    for(int off=1; off<32; off<<=1) mx = fmaxf(mx, __shfl_xor(mx, off));
    if(l32==0) mS[s] = mx;
  }
  __syncthreads();
  #pragma unroll
  for(int s=0;s<8;s++) pl[s][t] = __expf(lg[s] - mS[s]);
  __syncthreads();
  {  // per-s chunk sum of exp
    int s = t>>5, l32 = t&31;
    float sm = 0.f;
    #pragma unroll
    for(int k=0;k<8;k++) sm += pl[s][l32 + 32*k];
    #pragma unroll
    for(int off=1; off<32; off<<=1) sm += __shfl_xor(sm, off);
    if(l32==0) lS[s] = sm;
  }
  // acc[s] for d = t : sum_n p[s][n] * xn[n][t]
  float acc[8]={0,0,0,0,0,0,0,0};
  const u16* xc = xn + ((size_t)(b*NN) + (size_t)c*CHK)*DD + t;
  #pragma unroll 4
  for(int n=0;n<256;++n){
    float xv = bflo((u32)xc[(size_t)n*DD]);
    #pragma unroll
    for(int s=0;s<8;s++) acc[s] += pl[s][n]*xv;
  }
  __syncthreads();
  size_t pb = (size_t)(b*NCH + c)*8;
  #pragma unroll
  for(int s=0;s<8;s++) aP[pb*256 + s*256 + t] = acc[s];
  if(t<8){ mP[pb+t] = mS[t]; lP[pb+t] = lS[t]; }
}

// ---- combine chunk partials -> u' = attn@xn ----
__global__ __launch_bounds__(256) void k_comb(const float* __restrict__ mP, const float* __restrict__ lP,
                                              const float* __restrict__ aP, float* __restrict__ U){
  int r = blockIdx.x;            // r = b*8 + s
  int b = r>>3, s = r&7, t = threadIdx.x;
  float M = -1e30f;
  #pragma unroll
  for(int c=0;c<8;c++) M = fmaxf(M, mP[(b*NCH+c)*8 + s]);
  float w[8]; float L = 0.f;
  #pragma unroll
  for(int c=0;c<8;c++){ w[c] = __expf(mP[(b*NCH+c)*8+s] - M); L += lP[(b*NCH+c)*8+s]*w[c]; }
  float u = 0.f;
  #pragma unroll
  for(int c=0;c<8;c++) u += w[c]*aP[(size_t)((b*NCH+c)*8+s)*256 + t];
  U[r*256+t] = u / L;
}

// ---- generic small GEMM: C = act(A[M,256] @ W[NC,256]^T + bias), direct-from-L2, 4x4 micro ----
template<int NC, int MODE>
__device__ __forceinline__ void gemm_body(const float* __restrict__ A, const float* __restrict__ W,
                                          const float* __restrict__ bias, const float* __restrict__ R,
                                          float* __restrict__ C){
  const int tx = threadIdx.x & 15, ty = threadIdx.x >> 4;
  const int r0 = blockIdx.x*64 + ty*4, c0 = blockIdx.y*64 + tx*4;
  const float* a0 = A + (size_t)r0*256;
  const float* w0 = W + (size_t)c0*256;
  float acc[4][4] = {};
  #pragma unroll 2
  for(int k=0;k<256;k+=4){
    float4 av[4], wv[4];
    #pragma unroll
    for(int i=0;i<4;i++) av[i] = *(const float4*)(a0 + i*256 + k);
    #pragma unroll
    for(int j=0;j<4;j++) wv[j] = *(const float4*)(w0 + j*256 + k);
    #pragma unroll
    for(int i=0;i<4;i++)
      #pragma unroll
      for(int j=0;j<4;j++)
        acc[i][j] += av[i].x*wv[j].x + av[i].y*wv[j].y + av[i].z*wv[j].z + av[i].w*wv[j].w;
  }
  #pragma unroll
  for(int i=0;i<4;i++){
    #pragma unroll
    for(int j=0;j<4;j++){
      float v = acc[i][j] + bias[c0+j];
      if(MODE==1) v = fmaxf(v, 0.f);
      if(MODE==2) v += R[(size_t)(r0+i)*NC + c0 + j];
      C[(size_t)(r0+i)*NC + c0 + j] = v;
    }
  }
}

__global__ __launch_bounds__(256) void k_gigh(const float* __restrict__ U, const float* __restrict__ Wihv,
                                              const float* __restrict__ bihv, const float* __restrict__ Sc,
                                              const float* __restrict__ Whh, const float* __restrict__ bhh,
                                              float* __restrict__ Gi, float* __restrict__ Gh){
  if(blockIdx.z==0) gemm_body<768,0>(U,  Wihv, bihv, nullptr, Gi);
  else              gemm_body<768,0>(Sc, Whh,  bhh,  nullptr, Gh);
}
__global__ __launch_bounds__(256) void k_w1(const float* __restrict__ Ln, const float* __restrict__ W1m,
                                            const float* __restrict__ b1v, float* __restrict__ H){
  gemm_body<256,1>(Ln, W1m, b1v, nullptr, H);
}
__global__ __launch_bounds__(256) void k_w2(const float* __restrict__ H, const float* __restrict__ W2m,
                                            const float* __restrict__ b2v, const float* __restrict__ Sg,
                                            float* __restrict__ C){
  gemm_body<256,2>(H, W2m, b2v, Sg, C);
}

// ---- GRU gates + LN_ff fused; one block per row ----
__global__ __launch_bounds__(256) void k_gates(const float* __restrict__ Gi, const float* __restrict__ Gh,
                                               const float* __restrict__ Sc, const float* __restrict__ g,
                                               const float* __restrict__ be, float* __restrict__ Sg,
                                               float* __restrict__ Ln){
  __shared__ float sh[8];
  int r = blockIdx.x, t = threadIdx.x;
  const float* gi = Gi + (size_t)r*768;
  const float* gh = Gh + (size_t)r*768;
  float ir=gi[t], iz=gi[256+t], inn=gi[512+t];
  float hr=gh[t], hz=gh[256+t], hn=gh[512+t];
  float rr = 1.f/(1.f + __expf(-(ir+hr)));
  float zz = 1.f/(1.f + __expf(-(iz+hz)));
  float nn = tanhf(inn + rr*hn);
  float prev = Sc[r*256+t];
  float sp = (1.f-zz)*nn + zz*prev;
  Sg[r*256+t] = sp;
  float2 mr = block_meanrstd(sp, sh);
  Ln[r*256+t] = (sp-mr.x)*mr.y*g[t] + be[t];
}

extern "C" void kernel_launch(void* const* d_in, const int* in_sizes, int n_in,
                              void* d_out, int out_size, void* d_ws, size_t ws_size,
                              hipStream_t stream){
  const float* x    = (const float*)d_in[0];
  const float* noise= (const float*)d_in[1];
  const float* mu   = (const float*)d_in[2];
  const float* sig  = (const float*)d_in[3];
  const float* Wq   = (const float*)d_in[4];
  const float* bq   = (const float*)d_in[5];
  const float* Wk   = (const float*)d_in[6];
  // d_in[7] = bk : constant shift over n, cancels in softmax
  const float* Wv   = (const float*)d_in[8];
  const float* bv   = (const float*)d_in[9];
  const float* W_ih = (const float*)d_in[10];
  const float* b_ih = (const float*)d_in[11];
  const float* W_hh = (const float*)d_in[12];
  const float* b_hh = (const float*)d_in[13];
  const float* W1m  = (const float*)d_in[14];
  const float* b1v  = (const float*)d_in[15];
  const float* W2m  = (const float*)d_in[16];
  const float* b2v  = (const float*)d_in[17];
  const float* g_in = (const float*)d_in[18];
  const float* be_in= (const float*)d_in[19];
  const float* g_sl = (const float*)d_in[20];
  const float* be_sl= (const float*)d_in[21];
  const float* g_ff = (const float*)d_in[22];
  const float* be_ff= (const float*)d_in[23];

  char* p = (char*)d_ws;
  auto alloc = [&](size_t bytes)->char*{ char* q = p; p += (bytes + 255) & ~(size_t)255; return q; };
  u16*   xn   = (u16*)  alloc((size_t)BB*NN*DD*2);
  float* Wqk  = (float*)alloc(256*256*4);
  float* bqk  = (float*)alloc(256*4);
  float* Wihv = (float*)alloc(768*256*4);
  float* bihv = (float*)alloc(768*4);
  float* Scur = (float*)alloc(512*256*4);
  float* Sg   = (float*)alloc(512*256*4);
  float* Ln   = (float*)alloc(512*256*4);
  float* Hh   = (float*)alloc(512*256*4);
  float* Uu   = (float*)alloc(512*256*4);
  float* Qq   = (float*)alloc(512*256*4);
  float* Gi   = (float*)alloc((size_t)512*768*4);
  float* Gh   = (float*)alloc((size_t)512*768*4);
  float* mP   = (float*)alloc(64*8*8*4);
  float* lP   = (float*)alloc(64*8*8*4);
  float* aP   = (float*)alloc((size_t)64*8*8*256*4);
  if((size_t)(p - (char*)d_ws) > ws_size) return;  // ws too small -> fail loudly (output stays poisoned)

  k_prep<<<512, 256, 0, stream>>>(noise, mu, sig, Scur);
  k_wpre<<<1026, 256, 0, stream>>>(Wq, Wk, bq, W_ih, Wv, bv, b_ih, Wqk, bqk, Wihv, bihv);
  k_ln<<<32768, 256, 0, stream>>>(x, g_in, be_in, xn);

  for(int it=0; it<NITER; ++it){
    k_q<<<512, 256, 0, stream>>>(Scur, g_sl, be_sl, Wqk, bqk, Qq);
    k_attn<<<dim3(64, NCH), 256, 0, stream>>>(xn, Qq, mP, lP, aP);
    k_comb<<<512, 256, 0, stream>>>(mP, lP, aP, Uu);
    k_gigh<<<dim3(8,12,2), 256, 0, stream>>>(Uu, Wihv, bihv, Scur, W_hh, b_hh, Gi, Gh);
    k_gates<<<512, 256, 0, stream>>>(Gi, Gh, Scur, g_ff, be_ff, Sg, Ln);
    k_w1<<<dim3(8,4), 256, 0, stream>>>(Ln, W1m, b1v, Hh);
    float* outp = (it==NITER-1) ? (float*)d_out : Scur;
    k_w2<<<dim3(8,4), 256, 0, stream>>>(Hh, W2m, b2v, Sg, outp);
  }
}